// Round 1
// baseline (545.841 us; speedup 1.0000x reference)
//
#include <hip/hip_runtime.h>
#include <hip/hip_bf16.h>

#define Bb 2
#define Tt 2048
#define Dd 1024
#define Hh 16

typedef short s16x8 __attribute__((ext_vector_type(8)));
typedef float f32x4 __attribute__((ext_vector_type(4)));
typedef unsigned short u16;
typedef short mfma_in_t __attribute__((ext_vector_type(8)));  // guide-verified operand type for gfx950 bf16 MFMA

__device__ inline u16 f2bf(float f) {
  union { float f; unsigned u; } v; v.f = f;
  unsigned r = v.u + 0x7FFF + ((v.u >> 16) & 1);
  return (u16)(r >> 16);
}

__device__ inline f32x4 MFMA(s16x8 a, s16x8 b, f32x4 c) {
  return __builtin_amdgcn_mfma_f32_16x16x32_bf16(
      __builtin_bit_cast(mfma_in_t, a), __builtin_bit_cast(mfma_in_t, b), c, 0, 0, 0);
}

// ---------------- LayerNorm: fp32 in -> bf16 out ----------------
__global__ __launch_bounds__(256) void ln_kernel(const float* __restrict__ x,
    const float* __restrict__ w, const float* __restrict__ b, u16* __restrict__ out) {
  int row = blockIdx.x;
  const float4 v = ((const float4*)(x + (size_t)row * Dd))[threadIdx.x];
  float s = v.x + v.y + v.z + v.w;
  float sq = v.x * v.x + v.y * v.y + v.z * v.z + v.w * v.w;
#pragma unroll
  for (int off = 32; off; off >>= 1) { s += __shfl_down(s, off); sq += __shfl_down(sq, off); }
  __shared__ float red[8];
  int wid = threadIdx.x >> 6;
  if ((threadIdx.x & 63) == 0) { red[wid] = s; red[4 + wid] = sq; }
  __syncthreads();
  s = red[0] + red[1] + red[2] + red[3];
  sq = red[4] + red[5] + red[6] + red[7];
  float mean = s * (1.0f / Dd);
  float var = sq * (1.0f / Dd) - mean * mean;
  float rs = rsqrtf(var + 1e-5f);
  float4 wv = ((const float4*)w)[threadIdx.x];
  float4 bv = ((const float4*)b)[threadIdx.x];
  ushort4 o = make_ushort4(f2bf((v.x - mean) * rs * wv.x + bv.x),
                           f2bf((v.y - mean) * rs * wv.y + bv.y),
                           f2bf((v.z - mean) * rs * wv.z + bv.z),
                           f2bf((v.w - mean) * rs * wv.w + bv.w));
  ((ushort4*)(out + (size_t)row * Dd))[threadIdx.x] = o;
}

// ---------------- fp32 -> bf16 bulk convert (for Er) ----------------
__global__ __launch_bounds__(256) void cvt_kernel(const float* __restrict__ in, u16* __restrict__ out) {
  int i = blockIdx.x * 256 + threadIdx.x;  // 8 elements per thread
  const float4* p = (const float4*)in;
  float4 a = p[i * 2], b2 = p[i * 2 + 1];
  ((ushort4*)out)[i * 2]     = make_ushort4(f2bf(a.x), f2bf(a.y), f2bf(a.z), f2bf(a.w));
  ((ushort4*)out)[i * 2 + 1] = make_ushort4(f2bf(b2.x), f2bf(b2.y), f2bf(b2.z), f2bf(b2.w));
}

// ---------------- GEMM: C[M,N] = A[M,K](bf16) @ W[N,K](fp32)^T ----------------
// EPI 0: qkv  (3-way W select, bf16 out, ld 3072)
// EPI 1: fc1  (+bias, gelu, bf16 out, ld 4096)
// EPI 2: fc2  (+bias +residual, fp32 out, ld 1024)
template <int EPI>
__global__ __launch_bounds__(256) void gemm_bt(
    const u16* __restrict__ A,
    const float* __restrict__ W0, const float* __restrict__ W1, const float* __restrict__ W2,
    const float* __restrict__ bias, const float* __restrict__ res,
    void* __restrict__ outp, int K, int ldout) {
  __shared__ u16 As[128 * 40];  // rows padded to 80B: stride-80 => worst 2-way bank aliasing (free)
  __shared__ u16 Bs[128 * 40];
  const int bm = blockIdx.x, bn = blockIdx.y;
  const float* W; int nbase;
  if constexpr (EPI == 0) {
    int seg = bn >> 3;
    W = (seg == 0) ? W0 : (seg == 1) ? W1 : W2;
    nbase = (bn & 7) * 128;
  } else {
    W = W0; nbase = bn * 128;
  }
  const int t = threadIdx.x, lane = t & 63, wid = t >> 6;
  const int wm = wid >> 1, wn = wid & 1;
  const int l15 = lane & 15, l16 = lane >> 4;
  f32x4 acc[4][4] = {};
  const size_t abase = (size_t)(bm * 128) * K;
  const size_t bbase = (size_t)nbase * K;
  for (int k0 = 0; k0 < K; k0 += 32) {
#pragma unroll
    for (int i = 0; i < 2; i++) {  // stage A: 128x32 bf16
      int f = i * 256 + t;
      int row = f >> 2, ch = f & 3;
      s16x8 av = *(const s16x8*)(A + abase + (size_t)row * K + k0 + ch * 8);
      *(s16x8*)&As[row * 40 + ch * 8] = av;
    }
#pragma unroll
    for (int i = 0; i < 4; i++) {  // stage W: 128x32 fp32 -> bf16
      int f = i * 256 + t;
      int row = f >> 3, ch = f & 7;
      float4 wv = *(const float4*)(W + bbase + (size_t)row * K + k0 + ch * 4);
      *(ushort4*)&Bs[row * 40 + ch * 4] = make_ushort4(f2bf(wv.x), f2bf(wv.y), f2bf(wv.z), f2bf(wv.w));
    }
    __syncthreads();
    s16x8 af[4], bfr[4];
#pragma unroll
    for (int rt = 0; rt < 4; rt++) af[rt] = *(const s16x8*)&As[(wm * 64 + rt * 16 + l15) * 40 + l16 * 8];
#pragma unroll
    for (int ct = 0; ct < 4; ct++) bfr[ct] = *(const s16x8*)&Bs[(wn * 64 + ct * 16 + l15) * 40 + l16 * 8];
#pragma unroll
    for (int rt = 0; rt < 4; rt++)
#pragma unroll
      for (int ct = 0; ct < 4; ct++)
        acc[rt][ct] = MFMA(af[rt], bfr[ct], acc[rt][ct]);
    __syncthreads();
  }
  const int rg0 = bm * 128 + wm * 64 + l16 * 4;
  const int cg0 = bn * 128 + wn * 64 + l15;
#pragma unroll
  for (int rt = 0; rt < 4; rt++) {
#pragma unroll
    for (int ct = 0; ct < 4; ct++) {
#pragma unroll
      for (int j = 0; j < 4; j++) {
        int r = rg0 + rt * 16 + j;
        int c = cg0 + ct * 16;
        float v = acc[rt][ct][j];
        if constexpr (EPI == 0) {
          ((u16*)outp)[(size_t)r * ldout + c] = f2bf(v);
        } else if constexpr (EPI == 1) {
          v += bias[c];
          float g = 0.5f * v * (1.0f + tanhf(0.7978845608f * (v + 0.044715f * v * v * v)));
          ((u16*)outp)[(size_t)r * ldout + c] = f2bf(g);
        } else {
          v += bias[c] + res[(size_t)r * Dd + c];
          ((float*)outp)[(size_t)r * ldout + c] = v;
        }
      }
    }
  }
}

// ---------------- Flash attention with relative-position (skew) term ----------------
// logit[i,j] = (q_i . k_j + q_i . Er[h, T-1-i+j]) / 8, causal.
// WG: 64 q-rows (4 waves x 16), loop K-tiles of 64. Per wave the Er term is a
// banded GEMM G = Q[16,64] @ ErBand[80,64]^T, gathered as G[di, dj-di+15].
__global__ __launch_bounds__(256) void attn_kernel(
    const u16* __restrict__ qkv,   // [B*T, 3072] bf16 (q|k|v)
    const u16* __restrict__ Erb,   // [H, T, 64] bf16
    const float* __restrict__ x,
    float* __restrict__ x2) {
  __shared__ u16 Ksm[64 * 72];     // K tile [key][hd], stride 72 (144B) ; reused as per-wave P
  __shared__ u16 Vsm[64 * 72];     // V^T tile [hd][key]
  __shared__ u16 Esm[128 * 72];    // Er band [128 rows][hd]
  __shared__ float Gsm[4][16 * 80];  // per-wave banded QEr result
  const int qt = blockIdx.x, h = blockIdx.y, b = blockIdx.z;
  const int qi = qt * 64;
  const int t = threadIdx.x, lane = t & 63, w = t >> 6;
  const int l15 = lane & 15, l16 = lane >> 4;
  const u16* qp = qkv + (size_t)(b * Tt + qi + w * 16 + l15) * 3072 + h * 64 + l16 * 8;
  const s16x8 qf0 = *(const s16x8*)qp;
  const s16x8 qf1 = *(const s16x8*)(qp + 32);
  f32x4 o_acc[4] = {};
  float m_r[4] = {-1e30f, -1e30f, -1e30f, -1e30f};
  float l_r[4] = {0.f, 0.f, 0.f, 0.f};
  for (int kj = 0; kj <= qi; kj += 64) {
    // ---- stage K, V^T ----
#pragma unroll
    for (int i = 0; i < 2; i++) {
      int f = i * 256 + t;
      int row = f >> 3, ch = f & 7;
      const u16* kp = qkv + (size_t)(b * Tt + kj + row) * 3072 + Dd + h * 64 + ch * 8;
      s16x8 kv = *(const s16x8*)kp;
      *(s16x8*)&Ksm[row * 72 + ch * 8] = kv;
      s16x8 vv = *(const s16x8*)(kp + Dd);
#pragma unroll
      for (int e = 0; e < 8; e++) Vsm[(ch * 8 + e) * 72 + row] = (u16)vv[e];
    }
    // ---- stage Er band (bf16) ----
    const int rlo = Tt - 64 - qi + kj;
#pragma unroll
    for (int i = 0; i < 4; i++) {
      int f = i * 256 + t;
      int row = f >> 3, ch = f & 7;
      int r = rlo + row; r = (r > Tt - 1) ? Tt - 1 : r;  // OOB rows are masked later
      s16x8 ev = *(const s16x8*)(Erb + ((size_t)h * Tt + r) * 64 + ch * 8);
      *(s16x8*)&Esm[row * 72 + ch * 8] = ev;
    }
    __syncthreads();
    // ---- QK^T ----
    f32x4 s_acc[4] = {};
#pragma unroll
    for (int ct = 0; ct < 4; ct++) {
      int col = ct * 16 + l15;
      s16x8 k0 = *(const s16x8*)&Ksm[col * 72 + l16 * 8];
      s16x8 k1 = *(const s16x8*)&Ksm[col * 72 + 32 + l16 * 8];
      s_acc[ct] = MFMA(qf0, k0, s_acc[ct]);
      s_acc[ct] = MFMA(qf1, k1, s_acc[ct]);
    }
    // ---- banded Q @ ErBand^T ----
    const int ub = 48 - 16 * w;
    float* gw = Gsm[w];
#pragma unroll
    for (int g = 0; g < 5; g++) {
      f32x4 ga = {};
      int ur = ub + g * 16 + l15;
      s16x8 e0 = *(const s16x8*)&Esm[ur * 72 + l16 * 8];
      s16x8 e1 = *(const s16x8*)&Esm[ur * 72 + 32 + l16 * 8];
      ga = MFMA(qf0, e0, ga);
      ga = MFMA(qf1, e1, ga);
#pragma unroll
      for (int j = 0; j < 4; j++) gw[(l16 * 4 + j) * 80 + g * 16 + l15] = ga[j];
    }
    // ---- gather + online softmax (per-wave private LDS; compiler orders lgkmcnt) ----
    float p[4][4];
#pragma unroll
    for (int j = 0; j < 4; j++) {
      const int di = l16 * 4 + j;
      const int ig = qi + w * 16 + di;
      float rm = -1e30f;
#pragma unroll
      for (int ct = 0; ct < 4; ct++) {
        int dj = ct * 16 + l15;
        float s = -1e30f;
        if (kj + dj <= ig) s = (s_acc[ct][j] + gw[di * 80 + dj - di + 15]) * 0.125f;
        p[j][ct] = s;
        rm = fmaxf(rm, s);
      }
#pragma unroll
      for (int off = 1; off < 16; off <<= 1) rm = fmaxf(rm, __shfl_xor(rm, off));
      float mnew = fmaxf(m_r[j], rm);
      float alpha = __expf(m_r[j] - mnew);
      float rsum = 0.f;
#pragma unroll
      for (int ct = 0; ct < 4; ct++) { float pe = __expf(p[j][ct] - mnew); p[j][ct] = pe; rsum += pe; }
#pragma unroll
      for (int off = 1; off < 16; off <<= 1) rsum += __shfl_xor(rsum, off);
      l_r[j] = l_r[j] * alpha + rsum;
      m_r[j] = mnew;
#pragma unroll
      for (int g = 0; g < 4; g++) o_acc[g][j] *= alpha;
    }
    __syncthreads();  // all waves past their Ksm reads before P overwrites it
    // ---- P -> LDS (A-frag layout), PV ----
    u16* Pw = Ksm + w * 16 * 72;
#pragma unroll
    for (int j = 0; j < 4; j++)
#pragma unroll
      for (int ct = 0; ct < 4; ct++)
        Pw[(l16 * 4 + j) * 72 + ct * 16 + l15] = f2bf(p[j][ct]);
    s16x8 pa0 = *(const s16x8*)&Pw[l15 * 72 + l16 * 8];
    s16x8 pa1 = *(const s16x8*)&Pw[l15 * 72 + 32 + l16 * 8];
#pragma unroll
    for (int g = 0; g < 4; g++) {
      s16x8 v0 = *(const s16x8*)&Vsm[(g * 16 + l15) * 72 + l16 * 8];
      s16x8 v1 = *(const s16x8*)&Vsm[(g * 16 + l15) * 72 + 32 + l16 * 8];
      o_acc[g] = MFMA(pa0, v0, o_acc[g]);
      o_acc[g] = MFMA(pa1, v1, o_acc[g]);
    }
    __syncthreads();  // protect Ksm(P)/Vsm/Esm before next stage
  }
  // ---- epilogue: x2 = x + attn ----
#pragma unroll
  for (int g = 0; g < 4; g++)
#pragma unroll
    for (int j = 0; j < 4; j++) {
      int r = qi + w * 16 + l16 * 4 + j;
      int c = h * 64 + g * 16 + l15;
      size_t idx = (size_t)(b * Tt + r) * Dd + c;
      x2[idx] = x[idx] + o_acc[g][j] / l_r[j];
    }
}

extern "C" void kernel_launch(void* const* d_in, const int* in_sizes, int n_in,
                              void* d_out, int out_size, void* d_ws, size_t ws_size,
                              hipStream_t stream) {
  const float* x     = (const float*)d_in[0];
  const float* wq    = (const float*)d_in[1];
  const float* wk    = (const float*)d_in[2];
  const float* wv    = (const float*)d_in[3];
  const float* Er    = (const float*)d_in[4];
  const float* fc1_w = (const float*)d_in[5];
  const float* fc1_b = (const float*)d_in[6];
  const float* fc2_w = (const float*)d_in[7];
  const float* fc2_b = (const float*)d_in[8];
  const float* ln1_w = (const float*)d_in[9];
  const float* ln1_b = (const float*)d_in[10];
  const float* ln2_w = (const float*)d_in[11];
  const float* ln2_b = (const float*)d_in[12];

  char* ws = (char*)d_ws;
  u16*   h1  = (u16*)ws;                    //  8 MB  [4096,1024] bf16 (reused for h2)
  u16*   qkv = (u16*)(ws + 8388608);        // 24 MB  [4096,3072] bf16
  float* x2  = (float*)(ws + 33554432);     // 16 MB  [4096,1024] fp32
  u16*   a1  = (u16*)(ws + 50331648);       // 32 MB  [4096,4096] bf16
  u16*   erb = (u16*)(ws + 83886080);       //  4 MB  [16,2048,64] bf16
  float* out = (float*)d_out;

  ln_kernel<<<dim3(Bb * Tt), 256, 0, stream>>>(x, ln1_w, ln1_b, h1);
  cvt_kernel<<<dim3(1024), 256, 0, stream>>>(Er, erb);
  gemm_bt<0><<<dim3(32, 24), 256, 0, stream>>>(h1, wq, wk, wv, nullptr, nullptr, qkv, Dd, 3072);
  attn_kernel<<<dim3(Tt / 64, Hh, Bb), 256, 0, stream>>>(qkv, erb, x, x2);
  ln_kernel<<<dim3(Bb * Tt), 256, 0, stream>>>(x2, ln2_w, ln2_b, h1);
  gemm_bt<1><<<dim3(32, 32), 256, 0, stream>>>(h1, fc1_w, nullptr, nullptr, fc1_b, nullptr, a1, Dd, 4096);
  gemm_bt<2><<<dim3(32, 8), 256, 0, stream>>>(a1, fc2_w, nullptr, nullptr, fc2_b, x2, out, 4096, Dd);
}

// Round 4
// 425.303 us; speedup vs baseline: 1.2834x; 1.2834x over previous
//
#include <hip/hip_runtime.h>
#include <hip/hip_bf16.h>

#define Bb 2
#define Tt 2048
#define Dd 1024
#define Hh 16

typedef short s16x8 __attribute__((ext_vector_type(8)));
typedef float f32x4 __attribute__((ext_vector_type(4)));
typedef unsigned short u16;
typedef short mfma_in_t __attribute__((ext_vector_type(8)));

typedef const __attribute__((address_space(1))) void gvoid;
typedef __attribute__((address_space(3))) void lvoid;

__device__ inline u16 f2bf(float f) {
  union { float f; unsigned u; } v; v.f = f;
  unsigned r = v.u + 0x7FFF + ((v.u >> 16) & 1);
  return (u16)(r >> 16);
}

__device__ inline f32x4 MFMA(s16x8 a, s16x8 b, f32x4 c) {
  return __builtin_amdgcn_mfma_f32_16x16x32_bf16(
      __builtin_bit_cast(mfma_in_t, a), __builtin_bit_cast(mfma_in_t, b), c, 0, 0, 0);
}

// ---------------- LayerNorm: fp32 in -> bf16 out ----------------
__global__ __launch_bounds__(256) void ln_kernel(const float* __restrict__ x,
    const float* __restrict__ w, const float* __restrict__ b, u16* __restrict__ out) {
  int row = blockIdx.x;
  const float4 v = ((const float4*)(x + (size_t)row * Dd))[threadIdx.x];
  float s = v.x + v.y + v.z + v.w;
  float sq = v.x * v.x + v.y * v.y + v.z * v.z + v.w * v.w;
#pragma unroll
  for (int off = 32; off; off >>= 1) { s += __shfl_down(s, off); sq += __shfl_down(sq, off); }
  __shared__ float red[8];
  int wid = threadIdx.x >> 6;
  if ((threadIdx.x & 63) == 0) { red[wid] = s; red[4 + wid] = sq; }
  __syncthreads();
  s = red[0] + red[1] + red[2] + red[3];
  sq = red[4] + red[5] + red[6] + red[7];
  float mean = s * (1.0f / Dd);
  float var = sq * (1.0f / Dd) - mean * mean;
  float rs = rsqrtf(var + 1e-5f);
  float4 wv = ((const float4*)w)[threadIdx.x];
  float4 bv = ((const float4*)b)[threadIdx.x];
  ushort4 o = make_ushort4(f2bf((v.x - mean) * rs * wv.x + bv.x),
                           f2bf((v.y - mean) * rs * wv.y + bv.y),
                           f2bf((v.z - mean) * rs * wv.z + bv.z),
                           f2bf((v.w - mean) * rs * wv.w + bv.w));
  ((ushort4*)(out + (size_t)row * Dd))[threadIdx.x] = o;
}

// ---------------- fp32 -> bf16 bulk convert ----------------
__global__ __launch_bounds__(256) void cvt_kernel(const float* __restrict__ in, u16* __restrict__ out) {
  int i = blockIdx.x * 256 + threadIdx.x;  // 8 elements per thread
  const float4* p = (const float4*)in;
  float4 a = p[i * 2], b2 = p[i * 2 + 1];
  ((ushort4*)out)[i * 2]     = make_ushort4(f2bf(a.x), f2bf(a.y), f2bf(a.z), f2bf(a.w));
  ((ushort4*)out)[i * 2 + 1] = make_ushort4(f2bf(b2.x), f2bf(b2.y), f2bf(b2.z), f2bf(b2.w));
}

// ---------------- V transpose: qkv[tok][2048+h*64+d] -> vt[(b*H+h)*64+d][tok] ----------------
__global__ __launch_bounds__(256) void vtrans_kernel(const u16* __restrict__ qkv, u16* __restrict__ vt) {
  __shared__ u16 L[64 * 72];
  const int tok0 = blockIdx.x * 64, h = blockIdx.y, b = blockIdx.z;
  const int t = threadIdx.x;
#pragma unroll
  for (int i = 0; i < 2; i++) {
    int f = i * 256 + t;
    int row = f >> 3, ch = f & 7;  // row = token within tile
    *(s16x8*)&L[row * 72 + ch * 8] =
        *(const s16x8*)(qkv + (size_t)(b * Tt + tok0 + row) * 3072 + 2 * Dd + h * 64 + ch * 8);
  }
  __syncthreads();
#pragma unroll
  for (int i = 0; i < 2; i++) {
    int f = i * 256 + t;
    int d = f & 63, c = f >> 6;  // c = token chunk 0..7
    s16x8 o;
#pragma unroll
    for (int e = 0; e < 8; e++) o[e] = (short)L[(c * 8 + e) * 72 + d];
    *(s16x8*)(vt + ((size_t)(b * Hh + h) * 64 + d) * Tt + tok0 + c * 8) = o;
  }
}

// ---------------- GEMM: C[M,N] = A[M,K](bf16) @ W[N,K](bf16)^T, global_load_lds staging ----------------
// EPI 0: bf16 out            EPI 1: +bias, gelu, bf16 out     EPI 2: +bias +residual, fp32 out
template <int EPI>
__global__ __launch_bounds__(256) void gemm_bt(
    const u16* __restrict__ A, const u16* __restrict__ W,
    const float* __restrict__ bias, const float* __restrict__ res,
    void* __restrict__ outp, int K, int ldout) {
  __shared__ u16 As[128 * 32];  // linear dest, chunk-XOR-swizzled content
  __shared__ u16 Bs[128 * 32];
  const int bm = blockIdx.x, bn = blockIdx.y;
  const int t = threadIdx.x, lane = t & 63, w = t >> 6;
  const int wm = w >> 1, wn = w & 1;
  const int l15 = lane & 15, l16 = lane >> 4;
  f32x4 acc[4][4] = {};
  const u16* Abase = A + (size_t)(bm * 128) * K;
  const u16* Wbase = W + (size_t)(bn * 128) * K;
  // chunk q covers LDS u16 [q*512, q*512+512); lane L lands at q*512 + L*8 (16B/lane)
  const int frow = lane >> 2;                        // row within 16-row chunk
  const int fcol = ((lane & 3) ^ (frow & 3)) * 8;    // inverse-swizzled source column
  for (int k0 = 0; k0 < K; k0 += 32) {
#pragma unroll
    for (int i = 0; i < 2; i++) {
      int q = w * 2 + i;
      int row = q * 16 + frow;
      __builtin_amdgcn_global_load_lds((gvoid*)(Abase + (size_t)row * K + k0 + fcol),
                                       (lvoid*)&As[q * 512], 16, 0, 0);
      __builtin_amdgcn_global_load_lds((gvoid*)(Wbase + (size_t)row * K + k0 + fcol),
                                       (lvoid*)&Bs[q * 512], 16, 0, 0);
    }
    __syncthreads();
    s16x8 af[4], bfr[4];
#pragma unroll
    for (int rt = 0; rt < 4; rt++) {
      int ar = wm * 64 + rt * 16 + l15;
      af[rt] = *(const s16x8*)&As[ar * 32 + (l16 ^ (ar & 3)) * 8];
    }
#pragma unroll
    for (int ct = 0; ct < 4; ct++) {
      int br = wn * 64 + ct * 16 + l15;
      bfr[ct] = *(const s16x8*)&Bs[br * 32 + (l16 ^ (br & 3)) * 8];
    }
#pragma unroll
    for (int rt = 0; rt < 4; rt++)
#pragma unroll
      for (int ct = 0; ct < 4; ct++)
        acc[rt][ct] = MFMA(af[rt], bfr[ct], acc[rt][ct]);
    __syncthreads();
  }
  const int rg0 = bm * 128 + wm * 64 + l16 * 4;
  const int cg0 = bn * 128 + wn * 64 + l15;
#pragma unroll
  for (int rt = 0; rt < 4; rt++) {
#pragma unroll
    for (int ct = 0; ct < 4; ct++) {
#pragma unroll
      for (int j = 0; j < 4; j++) {
        int r = rg0 + rt * 16 + j;
        int c = cg0 + ct * 16;
        float v = acc[rt][ct][j];
        if constexpr (EPI == 0) {
          ((u16*)outp)[(size_t)r * ldout + c] = f2bf(v);
        } else if constexpr (EPI == 1) {
          v += bias[c];
          float g = 0.5f * v * (1.0f + tanhf(0.7978845608f * (v + 0.044715f * v * v * v)));
          ((u16*)outp)[(size_t)r * ldout + c] = f2bf(g);
        } else {
          v += bias[c] + res[(size_t)r * Dd + c];
          ((float*)outp)[(size_t)r * ldout + c] = v;
        }
      }
    }
  }
}

// ---------------- Flash attention with relative-position term ----------------
// Paired q-blocks: WG handles qt=blockIdx.x and qt=31-blockIdx.x  (34 K-tiles const -> flat balance).
// Per wave 16 q-rows. Er B-frags direct from global (L2); banded-G gathered via per-wave Gsm LDS
// (round-1-validated mechanism; bpermute variant under suspicion, bisected out this round).
__global__ __launch_bounds__(256) void attn_kernel(
    const u16* __restrict__ qkv,   // [B*T, 3072] bf16 (q|k|v)
    const u16* __restrict__ erb,   // [H, T, 64] bf16
    const u16* __restrict__ vt,    // [(B*H)*64+d, T] bf16  (V transposed)
    const float* __restrict__ x,
    float* __restrict__ x2) {
  __shared__ u16 Ksm[64 * 72];       // [key][hd]  stride 72 u16 (144B): 2-way aliasing only
  __shared__ u16 Vsm[64 * 72];       // [hd][key]  stride 72
  __shared__ u16 Psm[4][16 * 72];    // per-wave P [q][key] stride 72
  __shared__ float Gsm[4][16 * 80];  // per-wave banded QEr result [q][u]
  const int h = blockIdx.y, b = blockIdx.z;
  const int t = threadIdx.x, lane = t & 63, w = t >> 6;
  const int l15 = lane & 15, l16 = lane >> 4;
  u16* Pw = Psm[w];
  float* gw = Gsm[w];
  for (int pass = 0; pass < 2; ++pass) {
    const int qt = pass ? 31 - (int)blockIdx.x : (int)blockIdx.x;
    const int qi = qt * 64;
    const int qb = qi + w * 16;      // this wave's q-row base
    const u16* qp = qkv + (size_t)(b * Tt + qb + l15) * 3072 + h * 64 + l16 * 8;
    const s16x8 qf0 = *(const s16x8*)qp;
    const s16x8 qf1 = *(const s16x8*)(qp + 32);
    f32x4 o_acc[4] = {};
    float m_r[4] = {-1e30f, -1e30f, -1e30f, -1e30f};
    float l_r[4] = {0.f, 0.f, 0.f, 0.f};
    for (int kj = 0; kj <= qi; kj += 64) {
      // ---- stage K tile and V^T tile (vectorized, conflict-free) ----
#pragma unroll
      for (int i = 0; i < 2; i++) {
        int f = i * 256 + t;
        int row = f >> 3, ch = f & 7;
        *(s16x8*)&Ksm[row * 72 + ch * 8] =
            *(const s16x8*)(qkv + (size_t)(b * Tt + kj + row) * 3072 + Dd + h * 64 + ch * 8);
        *(s16x8*)&Vsm[row * 72 + ch * 8] =
            *(const s16x8*)(vt + ((size_t)(b * Hh + h) * 64 + row) * Tt + kj + ch * 8);
      }
      __syncthreads();
      // ---- QK^T ----
      f32x4 s_acc[4] = {};
#pragma unroll
      for (int ct = 0; ct < 4; ct++) {
        int col = ct * 16 + l15;
        s16x8 k0 = *(const s16x8*)&Ksm[col * 72 + l16 * 8];
        s16x8 k1 = *(const s16x8*)&Ksm[col * 72 + 32 + l16 * 8];
        s_acc[ct] = MFMA(qf1, k1, MFMA(qf0, k0, s_acc[ct]));
      }
      // ---- banded Q @ Er^T, B-frags direct from global (L2-resident), result -> wave-private Gsm ----
      const int rbase = Tt - 16 - qb + kj;  // >= 0
#pragma unroll
      for (int gt = 0; gt < 5; gt++) {
        int r = rbase + gt * 16 + l15;
        r = (r > Tt - 1) ? Tt - 1 : r;  // OOB rows feed masked entries only
        const u16* ep = erb + ((size_t)h * Tt + r) * 64 + l16 * 8;
        s16x8 e0 = *(const s16x8*)ep;
        s16x8 e1 = *(const s16x8*)(ep + 32);
        f32x4 z = {};
        f32x4 ga = MFMA(qf1, e1, MFMA(qf0, e0, z));
#pragma unroll
        for (int j = 0; j < 4; j++) gw[(l16 * 4 + j) * 80 + gt * 16 + l15] = ga[j];
      }
      // ---- gather srel from Gsm (wave-private), mask, online softmax ----
      float p[4][4];
#pragma unroll
      for (int j = 0; j < 4; j++) {
        const int di = l16 * 4 + j;
        const int ig = qb + di;
        float rm = -1e30f;
#pragma unroll
        for (int ct = 0; ct < 4; ct++) {
          int dj = ct * 16 + l15;
          float s = -1e30f;
          if (kj + dj <= ig) s = (s_acc[ct][j] + gw[di * 80 + dj - di + 15]) * 0.125f;
          p[j][ct] = s;
          rm = fmaxf(rm, s);
        }
#pragma unroll
        for (int o = 1; o < 16; o <<= 1) rm = fmaxf(rm, __shfl_xor(rm, o));
        float mnew = fmaxf(m_r[j], rm);
        float alpha = __expf(m_r[j] - mnew);
        float rsum = 0.f;
#pragma unroll
        for (int ct = 0; ct < 4; ct++) { float pe = __expf(p[j][ct] - mnew); p[j][ct] = pe; rsum += pe; }
#pragma unroll
        for (int o = 1; o < 16; o <<= 1) rsum += __shfl_xor(rsum, o);
        l_r[j] = l_r[j] * alpha + rsum;
        m_r[j] = mnew;
#pragma unroll
        for (int g = 0; g < 4; g++) o_acc[g][j] *= alpha;
      }
      // ---- P -> per-wave LDS (wave-private, no barrier), PV ----
#pragma unroll
      for (int j = 0; j < 4; j++)
#pragma unroll
        for (int ct = 0; ct < 4; ct++)
          Pw[(l16 * 4 + j) * 72 + ct * 16 + l15] = f2bf(p[j][ct]);
      s16x8 pa0 = *(const s16x8*)&Pw[l15 * 72 + l16 * 8];
      s16x8 pa1 = *(const s16x8*)&Pw[l15 * 72 + 32 + l16 * 8];
#pragma unroll
      for (int g = 0; g < 4; g++) {
        s16x8 v0 = *(const s16x8*)&Vsm[(g * 16 + l15) * 72 + l16 * 8];
        s16x8 v1 = *(const s16x8*)&Vsm[(g * 16 + l15) * 72 + 32 + l16 * 8];
        o_acc[g] = MFMA(pa1, v1, MFMA(pa0, v0, o_acc[g]));
      }
      __syncthreads();  // protect Ksm/Vsm before next staging
    }
    // ---- epilogue: x2 = x + attn ----
#pragma unroll
    for (int g = 0; g < 4; g++)
#pragma unroll
      for (int j = 0; j < 4; j++) {
        int r = qb + l16 * 4 + j;
        int c = h * 64 + g * 16 + l15;
        size_t idx = (size_t)(b * Tt + r) * Dd + c;
        x2[idx] = x[idx] + o_acc[g][j] / l_r[j];
      }
  }
}

extern "C" void kernel_launch(void* const* d_in, const int* in_sizes, int n_in,
                              void* d_out, int out_size, void* d_ws, size_t ws_size,
                              hipStream_t stream) {
  const float* x     = (const float*)d_in[0];
  const float* wq    = (const float*)d_in[1];
  const float* wk    = (const float*)d_in[2];
  const float* wv    = (const float*)d_in[3];
  const float* Er    = (const float*)d_in[4];
  const float* fc1_w = (const float*)d_in[5];
  const float* fc1_b = (const float*)d_in[6];
  const float* fc2_w = (const float*)d_in[7];
  const float* fc2_b = (const float*)d_in[8];
  const float* ln1_w = (const float*)d_in[9];
  const float* ln1_b = (const float*)d_in[10];
  const float* ln2_w = (const float*)d_in[11];
  const float* ln2_b = (const float*)d_in[12];

  const size_t MB = 1024 * 1024;
  char* ws = (char*)d_ws;
  u16*   h1   = (u16*)ws;                 // 0..8M    ln out (reused for ln2 out)
  u16*   qkv  = (u16*)(ws + 8 * MB);      // 8..32M   dead after attn
  u16*   vtb  = (u16*)(ws + 32 * MB);     // 32..40M  dead after attn
  u16*   erb  = (u16*)(ws + 40 * MB);     // 40..44M  dead after attn
  float* x2   = (float*)(ws + 44 * MB);   // 44..60M  alive to end
  u16*   wqkb = (u16*)(ws + 60 * MB);     // 60..66M  [3072,1024] bf16
  u16*   f1b  = (u16*)(ws + 66 * MB);     // 66..74M  [4096,1024] bf16
  u16*   f2b  = (u16*)(ws + 74 * MB);     // 74..82M  [1024,4096] bf16
  u16*   a1   = (u16*)(ws + 8 * MB);      // 8..40M   overlays qkv+vt (both dead)
  float* out  = (float*)d_out;

  ln_kernel<<<dim3(Bb * Tt), 256, 0, stream>>>(x, ln1_w, ln1_b, h1);
  cvt_kernel<<<dim3(1024), 256, 0, stream>>>(Er, erb);
  cvt_kernel<<<dim3(512), 256, 0, stream>>>(wq, wqkb);
  cvt_kernel<<<dim3(512), 256, 0, stream>>>(wk, wqkb + 1024 * 1024);
  cvt_kernel<<<dim3(512), 256, 0, stream>>>(wv, wqkb + 2 * 1024 * 1024);
  cvt_kernel<<<dim3(2048), 256, 0, stream>>>(fc1_w, f1b);
  cvt_kernel<<<dim3(2048), 256, 0, stream>>>(fc2_w, f2b);
  gemm_bt<0><<<dim3(32, 24), 256, 0, stream>>>(h1, wqkb, nullptr, nullptr, qkv, Dd, 3072);
  vtrans_kernel<<<dim3(32, 16, 2), 256, 0, stream>>>(qkv, vtb);
  attn_kernel<<<dim3(16, 16, 2), 256, 0, stream>>>(qkv, erb, vtb, x, x2);
  ln_kernel<<<dim3(Bb * Tt), 256, 0, stream>>>(x2, ln2_w, ln2_b, h1);
  gemm_bt<1><<<dim3(32, 32), 256, 0, stream>>>(h1, f1b, fc1_b, nullptr, a1, Dd, 4096);
  gemm_bt<2><<<dim3(32, 8), 256, 0, stream>>>(a1, f2b, fc2_b, x2, out, 4096, Dd);
}

// Round 5
// 333.203 us; speedup vs baseline: 1.6382x; 1.2764x over previous
//
#include <hip/hip_runtime.h>
#include <hip/hip_bf16.h>

#define Bb 2
#define Tt 2048
#define Dd 1024
#define Hh 16

typedef short s16x8 __attribute__((ext_vector_type(8)));
typedef float f32x4 __attribute__((ext_vector_type(4)));
typedef unsigned short u16;
typedef short mfma_in_t __attribute__((ext_vector_type(8)));

typedef const __attribute__((address_space(1))) void gvoid;
typedef __attribute__((address_space(3))) void lvoid;

__device__ inline u16 f2bf(float f) {
  union { float f; unsigned u; } v; v.f = f;
  unsigned r = v.u + 0x7FFF + ((v.u >> 16) & 1);
  return (u16)(r >> 16);
}

__device__ inline f32x4 MFMA(s16x8 a, s16x8 b, f32x4 c) {
  return __builtin_amdgcn_mfma_f32_16x16x32_bf16(
      __builtin_bit_cast(mfma_in_t, a), __builtin_bit_cast(mfma_in_t, b), c, 0, 0, 0);
}

// ---------------- LayerNorm: fp32 in -> bf16 out ----------------
__global__ __launch_bounds__(256) void ln_kernel(const float* __restrict__ x,
    const float* __restrict__ w, const float* __restrict__ b, u16* __restrict__ out) {
  int row = blockIdx.x;
  const float4 v = ((const float4*)(x + (size_t)row * Dd))[threadIdx.x];
  float s = v.x + v.y + v.z + v.w;
  float sq = v.x * v.x + v.y * v.y + v.z * v.z + v.w * v.w;
#pragma unroll
  for (int off = 32; off; off >>= 1) { s += __shfl_down(s, off); sq += __shfl_down(sq, off); }
  __shared__ float red[8];
  int wid = threadIdx.x >> 6;
  if ((threadIdx.x & 63) == 0) { red[wid] = s; red[4 + wid] = sq; }
  __syncthreads();
  s = red[0] + red[1] + red[2] + red[3];
  sq = red[4] + red[5] + red[6] + red[7];
  float mean = s * (1.0f / Dd);
  float var = sq * (1.0f / Dd) - mean * mean;
  float rs = rsqrtf(var + 1e-5f);
  float4 wv = ((const float4*)w)[threadIdx.x];
  float4 bv = ((const float4*)b)[threadIdx.x];
  ushort4 o = make_ushort4(f2bf((v.x - mean) * rs * wv.x + bv.x),
                           f2bf((v.y - mean) * rs * wv.y + bv.y),
                           f2bf((v.z - mean) * rs * wv.z + bv.z),
                           f2bf((v.w - mean) * rs * wv.w + bv.w));
  ((ushort4*)(out + (size_t)row * Dd))[threadIdx.x] = o;
}

// ---------------- fp32 -> bf16 bulk convert ----------------
__global__ __launch_bounds__(256) void cvt_kernel(const float* __restrict__ in, u16* __restrict__ out) {
  int i = blockIdx.x * 256 + threadIdx.x;  // 8 elements per thread
  const float4* p = (const float4*)in;
  float4 a = p[i * 2], b2 = p[i * 2 + 1];
  ((ushort4*)out)[i * 2]     = make_ushort4(f2bf(a.x), f2bf(a.y), f2bf(a.z), f2bf(a.w));
  ((ushort4*)out)[i * 2 + 1] = make_ushort4(f2bf(b2.x), f2bf(b2.y), f2bf(b2.z), f2bf(b2.w));
}

// ---------------- V transpose: qkv[tok][2048+h*64+d] -> vt[(b*H+h)*64+d][tok] ----------------
__global__ __launch_bounds__(256) void vtrans_kernel(const u16* __restrict__ qkv, u16* __restrict__ vt) {
  __shared__ u16 L[64 * 72];
  const int tok0 = blockIdx.x * 64, h = blockIdx.y, b = blockIdx.z;
  const int t = threadIdx.x;
#pragma unroll
  for (int i = 0; i < 2; i++) {
    int f = i * 256 + t;
    int row = f >> 3, ch = f & 7;  // row = token within tile
    *(s16x8*)&L[row * 72 + ch * 8] =
        *(const s16x8*)(qkv + (size_t)(b * Tt + tok0 + row) * 3072 + 2 * Dd + h * 64 + ch * 8);
  }
  __syncthreads();
#pragma unroll
  for (int i = 0; i < 2; i++) {
    int f = i * 256 + t;
    int d = f & 63, c = f >> 6;  // c = token chunk 0..7
    s16x8 o;
#pragma unroll
    for (int e = 0; e < 8; e++) o[e] = (short)L[(c * 8 + e) * 72 + d];
    *(s16x8*)(vt + ((size_t)(b * Hh + h) * 64 + d) * Tt + tok0 + c * 8) = o;
  }
}

// ---------------- GEMM: C[M,N] = A[M,K](bf16) @ W[N,K](bf16)^T ----------------
// Double-buffered global_load_lds pipeline, ONE barrier per K-step (T3-lite).
// EPI 0: bf16 out    EPI 1: +bias, gelu, bf16 out    EPI 2: +bias +residual, fp32 out
template <int EPI>
__global__ __launch_bounds__(256) void gemm_bt(
    const u16* __restrict__ A, const u16* __restrict__ W,
    const float* __restrict__ bias, const float* __restrict__ res,
    void* __restrict__ outp, int K, int ldout) {
  __shared__ u16 As[2][128 * 32];  // linear dest, chunk-XOR-swizzled content
  __shared__ u16 Bs[2][128 * 32];
  const int bm = blockIdx.x, bn = blockIdx.y;
  const int t = threadIdx.x, lane = t & 63, w = t >> 6;
  const int wm = w >> 1, wn = w & 1;
  const int l15 = lane & 15, l16 = lane >> 4;
  f32x4 acc[4][4] = {};
  const u16* Abase = A + (size_t)(bm * 128) * K;
  const u16* Wbase = W + (size_t)(bn * 128) * K;
  // chunk q covers LDS u16 [q*512, q*512+512); lane L lands at q*512 + L*8 (16B/lane)
  const int frow = lane >> 2;                        // row within 16-row chunk
  const int fcol = ((lane & 3) ^ (frow & 3)) * 8;    // inverse-swizzled source column
#define GEMM_STAGE(k0_, nb_)                                                            \
  _Pragma("unroll")                                                                     \
  for (int i = 0; i < 2; i++) {                                                         \
    int q = w * 2 + i;                                                                  \
    int row = q * 16 + frow;                                                            \
    __builtin_amdgcn_global_load_lds((gvoid*)(Abase + (size_t)row * K + (k0_) + fcol),  \
                                     (lvoid*)&As[nb_][q * 512], 16, 0, 0);              \
    __builtin_amdgcn_global_load_lds((gvoid*)(Wbase + (size_t)row * K + (k0_) + fcol),  \
                                     (lvoid*)&Bs[nb_][q * 512], 16, 0, 0);              \
  }
  GEMM_STAGE(0, 0);
  __syncthreads();
  int cur = 0;
  for (int k0 = 0; k0 < K; k0 += 32) {
    if (k0 + 32 < K) { GEMM_STAGE(k0 + 32, cur ^ 1); }
    s16x8 af[4], bfr[4];
#pragma unroll
    for (int rt = 0; rt < 4; rt++) {
      int ar = wm * 64 + rt * 16 + l15;
      af[rt] = *(const s16x8*)&As[cur][ar * 32 + (l16 ^ (ar & 3)) * 8];
    }
#pragma unroll
    for (int ct = 0; ct < 4; ct++) {
      int br = wn * 64 + ct * 16 + l15;
      bfr[ct] = *(const s16x8*)&Bs[cur][br * 32 + (l16 ^ (br & 3)) * 8];
    }
#pragma unroll
    for (int rt = 0; rt < 4; rt++)
#pragma unroll
      for (int ct = 0; ct < 4; ct++)
        acc[rt][ct] = MFMA(af[rt], bfr[ct], acc[rt][ct]);
    __syncthreads();  // implicit vmcnt(0)+lgkmcnt(0): next-buf loads landed, reads done
    cur ^= 1;
  }
  const int rg0 = bm * 128 + wm * 64 + l16 * 4;
  const int cg0 = bn * 128 + wn * 64 + l15;
#pragma unroll
  for (int rt = 0; rt < 4; rt++) {
#pragma unroll
    for (int ct = 0; ct < 4; ct++) {
#pragma unroll
      for (int j = 0; j < 4; j++) {
        int r = rg0 + rt * 16 + j;
        int c = cg0 + ct * 16;
        float v = acc[rt][ct][j];
        if constexpr (EPI == 0) {
          ((u16*)outp)[(size_t)r * ldout + c] = f2bf(v);
        } else if constexpr (EPI == 1) {
          v += bias[c];
          float u = 0.7978845608f * (v + 0.044715f * v * v * v);
          float th = 1.0f - 2.0f / (__expf(2.0f * u) + 1.0f);
          ((u16*)outp)[(size_t)r * ldout + c] = f2bf(0.5f * v * (1.0f + th));
        } else {
          v += bias[c] + res[(size_t)r * Dd + c];
          ((float*)outp)[(size_t)r * ldout + c] = v;
        }
      }
    }
  }
}

// ---------------- Flash attention with relative-position term ----------------
// Paired q-blocks (flat 34 K-tiles/WG). Per wave 16 q-rows. K/V/Er reg-prefetched
// one tile ahead (T14): loads issue right after the consume barrier, written to LDS
// at the top of the next iteration -> HBM/L2 latency hidden under compute.
__global__ __launch_bounds__(256, 2) void attn_kernel(
    const u16* __restrict__ qkv,   // [B*T, 3072] bf16 (q|k|v)
    const u16* __restrict__ erb,   // [H, T, 64] bf16
    const u16* __restrict__ vt,    // [(B*H)*64+d, T] bf16  (V transposed)
    const float* __restrict__ x,
    float* __restrict__ x2) {
  __shared__ u16 Ksm[64 * 72];       // [key][hd]  stride 72 u16 (144B)
  __shared__ u16 Vsm[64 * 72];       // [hd][key]  stride 72
  __shared__ u16 Esm[128 * 72];      // Er band [128 rows][hd]
  __shared__ float Gsm[4][16 * 82];  // per-wave banded QEr [q][u], stride 82 (2-way writes); P overlays
  const int h = blockIdx.y, b = blockIdx.z;
  const int t = threadIdx.x, lane = t & 63, w = t >> 6;
  const int l15 = lane & 15, l16 = lane >> 4;
  float* gw = Gsm[w];
  u16* Pw = (u16*)gw;                // union: P written only after all G gathers done
  const int tr = t >> 3, tc = (t & 7) * 8;
  const u16* kbase = qkv + ((size_t)b * Tt) * 3072 + Dd + h * 64;
  const u16* vbase = vt + ((size_t)(b * Hh + h) * 64) * Tt;
  const u16* ebase = erb + (size_t)h * Tt * 64;
  s16x8 kR0, kR1, vR0, vR1, eR0, eR1, eR2, eR3;
#define ATTN_PREFETCH(kjn_, qin_)                                              \
  {                                                                            \
    const int kjn = (kjn_);                                                    \
    kR0 = *(const s16x8*)(kbase + (size_t)(kjn + tr) * 3072 + tc);             \
    kR1 = *(const s16x8*)(kbase + (size_t)(kjn + 32 + tr) * 3072 + tc);        \
    vR0 = *(const s16x8*)(vbase + (size_t)tr * Tt + kjn + tc);                 \
    vR1 = *(const s16x8*)(vbase + (size_t)(32 + tr) * Tt + kjn + tc);          \
    const int rlo = Tt - 64 - (qin_) + kjn;                                    \
    int g0 = rlo + tr;          g0 = g0 > Tt - 1 ? Tt - 1 : g0;                \
    int g1 = rlo + 32 + tr;     g1 = g1 > Tt - 1 ? Tt - 1 : g1;                \
    int g2 = rlo + 64 + tr;     g2 = g2 > Tt - 1 ? Tt - 1 : g2;                \
    int g3 = rlo + 96 + tr;     g3 = g3 > Tt - 1 ? Tt - 1 : g3;                \
    eR0 = *(const s16x8*)(ebase + (size_t)g0 * 64 + tc);                       \
    eR1 = *(const s16x8*)(ebase + (size_t)g1 * 64 + tc);                       \
    eR2 = *(const s16x8*)(ebase + (size_t)g2 * 64 + tc);                       \
    eR3 = *(const s16x8*)(ebase + (size_t)g3 * 64 + tc);                       \
  }
  for (int pass = 0; pass < 2; ++pass) {
    const int qt = pass ? 31 - (int)blockIdx.x : (int)blockIdx.x;
    const int qi = qt * 64;
    const int qb = qi + w * 16;      // this wave's q-row base
    const u16* qp = qkv + (size_t)(b * Tt + qb + l15) * 3072 + h * 64 + l16 * 8;
    const s16x8 qf0 = *(const s16x8*)qp;
    const s16x8 qf1 = *(const s16x8*)(qp + 32);
    f32x4 o_acc[4] = {};
    float m_r[4] = {-1e30f, -1e30f, -1e30f, -1e30f};
    float l_r[4] = {0.f, 0.f, 0.f, 0.f};
    ATTN_PREFETCH(0, qi);
    for (int kj = 0; kj <= qi; kj += 64) {
      // ---- write prefetched tile to LDS ----
      *(s16x8*)&Ksm[tr * 72 + tc] = kR0;
      *(s16x8*)&Ksm[(32 + tr) * 72 + tc] = kR1;
      *(s16x8*)&Vsm[tr * 72 + tc] = vR0;
      *(s16x8*)&Vsm[(32 + tr) * 72 + tc] = vR1;
      *(s16x8*)&Esm[tr * 72 + tc] = eR0;
      *(s16x8*)&Esm[(32 + tr) * 72 + tc] = eR1;
      *(s16x8*)&Esm[(64 + tr) * 72 + tc] = eR2;
      *(s16x8*)&Esm[(96 + tr) * 72 + tc] = eR3;
      __syncthreads();
      // ---- issue next tile's loads (latency hidden under compute below) ----
      if (kj + 64 <= qi) {
        ATTN_PREFETCH(kj + 64, qi);
      } else if (pass == 0) {
        ATTN_PREFETCH(0, (31 - (int)blockIdx.x) * 64);
      }
      // ---- QK^T ----
      f32x4 s_acc[4] = {};
#pragma unroll
      for (int ct = 0; ct < 4; ct++) {
        int col = ct * 16 + l15;
        s16x8 k0 = *(const s16x8*)&Ksm[col * 72 + l16 * 8];
        s16x8 k1 = *(const s16x8*)&Ksm[col * 72 + 32 + l16 * 8];
        s_acc[ct] = MFMA(qf1, k1, MFMA(qf0, k0, s_acc[ct]));
      }
      // ---- banded Q @ Er^T from Esm -> wave-private Gsm ----
      const int ub = 48 - 16 * w;
#pragma unroll
      for (int gt = 0; gt < 5; gt++) {
        int ur = ub + gt * 16 + l15;
        s16x8 e0 = *(const s16x8*)&Esm[ur * 72 + l16 * 8];
        s16x8 e1 = *(const s16x8*)&Esm[ur * 72 + 32 + l16 * 8];
        f32x4 z = {};
        f32x4 ga = MFMA(qf1, e1, MFMA(qf0, e0, z));
#pragma unroll
        for (int j = 0; j < 4; j++) gw[(l16 * 4 + j) * 82 + gt * 16 + l15] = ga[j];
      }
      // ---- gather srel from Gsm (wave-private), mask, online softmax ----
      float p[4][4];
#pragma unroll
      for (int j = 0; j < 4; j++) {
        const int di = l16 * 4 + j;
        const int ig = qb + di;
        float rm = -1e30f;
#pragma unroll
        for (int ct = 0; ct < 4; ct++) {
          int dj = ct * 16 + l15;
          float s = -1e30f;
          if (kj + dj <= ig) s = (s_acc[ct][j] + gw[di * 82 + dj - di + 15]) * 0.125f;
          p[j][ct] = s;
          rm = fmaxf(rm, s);
        }
#pragma unroll
        for (int o = 1; o < 16; o <<= 1) rm = fmaxf(rm, __shfl_xor(rm, o));
        float mnew = fmaxf(m_r[j], rm);
        float alpha = __expf(m_r[j] - mnew);
        float rsum = 0.f;
#pragma unroll
        for (int ct = 0; ct < 4; ct++) { float pe = __expf(p[j][ct] - mnew); p[j][ct] = pe; rsum += pe; }
#pragma unroll
        for (int o = 1; o < 16; o <<= 1) rsum += __shfl_xor(rsum, o);
        l_r[j] = l_r[j] * alpha + rsum;
        m_r[j] = mnew;
#pragma unroll
        for (int g = 0; g < 4; g++) o_acc[g][j] *= alpha;
      }
      // ---- P -> per-wave LDS (overlays Gsm; all gw reads complete above), PV ----
#pragma unroll
      for (int j = 0; j < 4; j++)
#pragma unroll
        for (int ct = 0; ct < 4; ct++)
          Pw[(l16 * 4 + j) * 72 + ct * 16 + l15] = f2bf(p[j][ct]);
      s16x8 pa0 = *(const s16x8*)&Pw[l15 * 72 + l16 * 8];
      s16x8 pa1 = *(const s16x8*)&Pw[l15 * 72 + 32 + l16 * 8];
#pragma unroll
      for (int g = 0; g < 4; g++) {
        s16x8 v0 = *(const s16x8*)&Vsm[(g * 16 + l15) * 72 + l16 * 8];
        s16x8 v1 = *(const s16x8*)&Vsm[(g * 16 + l15) * 72 + 32 + l16 * 8];
        o_acc[g] = MFMA(pa1, v1, MFMA(pa0, v0, o_acc[g]));
      }
      __syncthreads();  // protect Ksm/Vsm/Esm before next tile's LDS writes
    }
    // ---- epilogue: x2 = x + attn ----
#pragma unroll
    for (int g = 0; g < 4; g++)
#pragma unroll
      for (int j = 0; j < 4; j++) {
        int r = qb + l16 * 4 + j;
        int c = h * 64 + g * 16 + l15;
        size_t idx = (size_t)(b * Tt + r) * Dd + c;
        x2[idx] = x[idx] + o_acc[g][j] / l_r[j];
      }
  }
}

extern "C" void kernel_launch(void* const* d_in, const int* in_sizes, int n_in,
                              void* d_out, int out_size, void* d_ws, size_t ws_size,
                              hipStream_t stream) {
  const float* x     = (const float*)d_in[0];
  const float* wq    = (const float*)d_in[1];
  const float* wk    = (const float*)d_in[2];
  const float* wv    = (const float*)d_in[3];
  const float* Er    = (const float*)d_in[4];
  const float* fc1_w = (const float*)d_in[5];
  const float* fc1_b = (const float*)d_in[6];
  const float* fc2_w = (const float*)d_in[7];
  const float* fc2_b = (const float*)d_in[8];
  const float* ln1_w = (const float*)d_in[9];
  const float* ln1_b = (const float*)d_in[10];
  const float* ln2_w = (const float*)d_in[11];
  const float* ln2_b = (const float*)d_in[12];

  const size_t MB = 1024 * 1024;
  char* ws = (char*)d_ws;
  u16*   h1   = (u16*)ws;                 // 0..8M    ln out (reused for ln2 out)
  u16*   qkv  = (u16*)(ws + 8 * MB);      // 8..32M   dead after attn
  u16*   vtb  = (u16*)(ws + 32 * MB);     // 32..40M  dead after attn
  u16*   erb  = (u16*)(ws + 40 * MB);     // 40..44M  dead after attn
  float* x2   = (float*)(ws + 44 * MB);   // 44..60M  alive to end
  u16*   wqkb = (u16*)(ws + 60 * MB);     // 60..66M  [3072,1024] bf16
  u16*   f1b  = (u16*)(ws + 66 * MB);     // 66..74M  [4096,1024] bf16
  u16*   f2b  = (u16*)(ws + 74 * MB);     // 74..82M  [1024,4096] bf16
  u16*   a1   = (u16*)(ws + 8 * MB);      // 8..40M   overlays qkv+vt (both dead)
  float* out  = (float*)d_out;

  ln_kernel<<<dim3(Bb * Tt), 256, 0, stream>>>(x, ln1_w, ln1_b, h1);
  cvt_kernel<<<dim3(1024), 256, 0, stream>>>(Er, erb);
  cvt_kernel<<<dim3(512), 256, 0, stream>>>(wq, wqkb);
  cvt_kernel<<<dim3(512), 256, 0, stream>>>(wk, wqkb + 1024 * 1024);
  cvt_kernel<<<dim3(512), 256, 0, stream>>>(wv, wqkb + 2 * 1024 * 1024);
  cvt_kernel<<<dim3(2048), 256, 0, stream>>>(fc1_w, f1b);
  cvt_kernel<<<dim3(2048), 256, 0, stream>>>(fc2_w, f2b);
  gemm_bt<0><<<dim3(32, 24), 256, 0, stream>>>(h1, wqkb, nullptr, nullptr, qkv, Dd, 3072);
  vtrans_kernel<<<dim3(32, 16, 2), 256, 0, stream>>>(qkv, vtb);
  attn_kernel<<<dim3(16, 16, 2), 256, 0, stream>>>(qkv, erb, vtb, x, x2);
  ln_kernel<<<dim3(Bb * Tt), 256, 0, stream>>>(x2, ln2_w, ln2_b, h1);
  gemm_bt<1><<<dim3(32, 32), 256, 0, stream>>>(h1, f1b, fc1_b, nullptr, a1, Dd, 4096);
  gemm_bt<2><<<dim3(32, 8), 256, 0, stream>>>(a1, f2b, fc2_b, x2, out, 4096, Dd);
}